// Round 6
// baseline (143.668 us; speedup 1.0000x reference)
//
#include <hip/hip_runtime.h>
#include <hip/hip_cooperative_groups.h>

namespace cg = cooperative_groups;

// MeanPooling: xs [B=16, T=2048, D=1024] fp32, xs_len [B] (int64 or int32), out [B, D] fp32.
// out[b][d] = sum_{t < len_b} xs[b][t][d] / len_b
//
// SINGLE cooperative dispatch (rounds 2-5 lesson: multi-dispatch graphs hide
// unknown inter-dispatch gaps; fuse so dur_us is unambiguous):
//   phase 1: 1024 blocks, proportional partition. Block i -> (sample b, slot j),
//            sums rows [j*len_b/cb, (j+1)*len_b/cb) into ws[i][0:1024].
//            Every assigned block WRITES its slot (zeros if empty range) so
//            phase 2 never reads uninitialized ws.
//   grid.sync()
//   phase 2: blocks 0..63 = (sample b, D-chunk c). Reduce slots [s0, s0+cb),
//            scale by 1/len_b, write out.

#define B_ 16
#define T_ 2048
#define D_ 1024
#define NB 1008          // target blocks; sum(cnt) <= NB + B_ = 1024 = grid
#define GRID 1024        // exactly 4 blocks per CU -> co-resident for grid.sync

__device__ __forceinline__ int load_len(const void* p, bool is64, int k)
{
    long long len = is64 ? ((const long long*)p)[k]
                         : (long long)((const int*)p)[k];
    if (len < 1) len = 1;
    if (len > T_) len = T_;
    return (int)len;
}

__device__ __forceinline__ bool sniff64(const void* p)
{
    // int64 storage: element 0 read as i64 is in [1, T_]. int32 storage:
    // the i64 read = len0 | (len1 << 32) >= 2^32 since len1 >= 1.
    const long long v0 = ((const long long*)p)[0];
    return (v0 >= 1 && v0 <= (long long)T_);
}

__global__ __launch_bounds__(256, 4) void mp_fused(
    const float* __restrict__ xs,
    const void* __restrict__ len_ptr,
    float* __restrict__ ws,
    float* __restrict__ out)
{
    const int bid = blockIdx.x;
    const int tid = threadIdx.x;
    const bool is64 = sniff64(len_ptr);

    unsigned total = 0;
    #pragma unroll
    for (int k = 0; k < B_; ++k) total += (unsigned)load_len(len_ptr, is64, k);

    // ---------- phase 1: balanced partial sums (array-free scan, rule #20) ----------
    int b = -1, j = 0, len = 1, cb = 1;
    {
        unsigned p = 0;
        #pragma unroll
        for (int k = 0; k < B_; ++k) {
            const int lk = load_len(len_ptr, is64, k);
            const int ck = (int)(((unsigned)lk * NB + total - 1u) / total);  // >= 1
            const bool hit = (b < 0) && ((unsigned)bid < p + (unsigned)ck);
            if (hit) { b = k; j = bid - (int)p; len = lk; cb = ck; }
            p += (unsigned)ck;
        }
    }

    if (b >= 0) {
        // products <= 2048*1008 < 2^31 -> cheap u32 division
        const int r0 = (int)(((unsigned)j * (unsigned)len) / (unsigned)cb);
        const int r1 = (int)(((unsigned)(j + 1) * (unsigned)len) / (unsigned)cb);

        const float4* src = ((const float4*)xs) + ((long)b * T_ + r0) * (D_ / 4) + tid;
        float4 acc = make_float4(0.f, 0.f, 0.f, 0.f);

        #pragma unroll 4
        for (int t = r0; t < r1; ++t) {
            float4 v = *src;
            src += (D_ / 4);
            acc.x += v.x; acc.y += v.y; acc.z += v.z; acc.w += v.w;
        }
        // write unconditionally (zeros if r0==r1) so phase 2 reads are defined
        ((float4*)ws)[(long)bid * (D_ / 4) + tid] = acc;
    }

    cg::this_grid().sync();

    // ---------- phase 2: 64 blocks reduce ----------
    __shared__ float4 sm[4][64];
    if (bid < B_ * 4) {
        const int bb = bid >> 2;     // sample
        const int c = bid & 3;       // D-chunk: 256 floats = 64 float4
        const int lane = tid & 63;
        const int w = tid >> 6;      // 4 waves stride the slots

        int s0 = 0, cb2 = 1, len2 = 1;
        {
            unsigned p = 0;
            #pragma unroll
            for (int k = 0; k < B_; ++k) {
                const int lk = load_len(len_ptr, is64, k);
                const int ck = (int)(((unsigned)lk * NB + total - 1u) / total);
                if (k == bb) { s0 = (int)p; cb2 = ck; len2 = lk; }
                p += (unsigned)ck;
            }
        }

        const int d4 = c * 64 + lane;    // float4 index in [0, 256)
        const float4* wsp = (const float4*)ws;

        float4 acc = make_float4(0.f, 0.f, 0.f, 0.f);
        #pragma unroll 4
        for (int s = s0 + w; s < s0 + cb2; s += 4) {
            float4 v = wsp[(long)s * (D_ / 4) + d4];
            acc.x += v.x; acc.y += v.y; acc.z += v.z; acc.w += v.w;
        }

        sm[w][lane] = acc;
        __syncthreads();

        if (w == 0) {
            float4 a0 = sm[0][lane], a1 = sm[1][lane], a2 = sm[2][lane], a3 = sm[3][lane];
            const float inv = 1.0f / (float)len2;
            float4 r;
            r.x = (a0.x + a1.x + a2.x + a3.x) * inv;
            r.y = (a0.y + a1.y + a2.y + a3.y) * inv;
            r.z = (a0.z + a1.z + a2.z + a3.z) * inv;
            r.w = (a0.w + a1.w + a2.w + a3.w) * inv;
            ((float4*)out)[(long)bb * (D_ / 4) + d4] = r;
        }
    }
}

extern "C" void kernel_launch(void* const* d_in, const int* in_sizes, int n_in,
                              void* d_out, int out_size, void* d_ws, size_t ws_size,
                              hipStream_t stream)
{
    const float* xs = (const float*)d_in[0];
    const void* xs_len = d_in[1];
    float* out = (float*)d_out;
    float* ws = (float*)d_ws;    // uses GRID * D_ * 4 B = 4 MiB

    void* args[] = { (void*)&xs, (void*)&xs_len, (void*)&ws, (void*)&out };
    hipLaunchCooperativeKernel((void*)mp_fused, dim3(GRID), dim3(256), args, 0, stream);
}

// Round 7
// 32.810 us; speedup vs baseline: 4.3788x; 4.3788x over previous
//
#include <hip/hip_runtime.h>

// MeanPooling: xs [B=16, T=2048, D=1024] fp32, xs_len [B] (int64 or int32), out [B, D] fp32.
// out[b][d] = sum_{t < len_b} xs[b][t][d] / len_b
//
// Two dispatches. K1 uses a DYNAMIC TICKET counter (in d_ws) for load balance:
//   - 256 blocks x 4 takes = exactly 1024 atomicAdds per replay.
//   - slice = ticket & 1023. 1024 divides 2^32, so any starting counter value
//     (incl. 0xAAAAAAAA poison) yields each slice exactly once per replay.
//     Counter is never reset; no init needed; output bit-identical per replay.
//   - take-ahead: next ticket is fetched before processing the current slice,
//     hiding the ~1 us cross-XCD atomic latency.
// K2 (64 blocks) reduces nact = ceil(len/32) slots per sample, scales, writes.

#define B_ 16
#define T_ 2048
#define D_ 1024
#define CH 32               // rows per slice
#define NSL 1024            // slices total = B_*(T_/CH); POWER OF 2 (rotation invariant)
#define G1 256              // K1 grid
#define TAKES (NSL / G1)    // 4 tickets per block
#define SLOT0_F4 64         // slot region starts at float4 index 64 (1 KiB header)

__device__ __forceinline__ bool sniff64(const void* p)
{
    // int64 storage: element 0 read as i64 is in [1, T_]. int32 storage:
    // the i64 read = len0 | (len1 << 32) >= 2^32 since len1 >= 1.
    const long long v0 = ((const long long*)p)[0];
    return (v0 >= 1 && v0 <= (long long)T_);
}

__device__ __forceinline__ int load_len(const void* p, bool is64, int k)
{
    long long len = is64 ? ((const long long*)p)[k]
                         : (long long)((const int*)p)[k];
    if (len < 1) len = 1;
    if (len > T_) len = T_;
    return (int)len;
}

__global__ __launch_bounds__(256) void mp_partial(
    const float* __restrict__ xs,
    const void* __restrict__ len_ptr,
    unsigned* __restrict__ ctr,      // d_ws byte 0
    float4* __restrict__ ws)         // d_ws as float4; slots at SLOT0_F4
{
    const int tid = threadIdx.x;     // 256 threads x float4 = full 1024-wide D row
    const bool is64 = sniff64(len_ptr);

    unsigned t_next = (tid == 0) ? 0u : 0u;
    // one ticket per BLOCK: lane 0 of wave 0 takes it, broadcast via LDS
    __shared__ unsigned sh_ticket;
    if (tid == 0) sh_ticket = atomicAdd(ctr, 1u);
    __syncthreads();
    t_next = sh_ticket;

    #pragma unroll 1
    for (int i = 0; i < TAKES; ++i) {
        const unsigned ticket = t_next;
        // take-ahead: issue next ticket before processing current
        if (i + 1 < TAKES) {
            __syncthreads();
            if (tid == 0) sh_ticket = atomicAdd(ctr, 1u);
        }

        const int s  = (int)(ticket & (NSL - 1));
        const int b  = s >> 6;           // 64 slices per sample
        const int sl = s & 63;
        const int len = load_len(len_ptr, is64, b);
        const int t0 = sl * CH;

        if (t0 < len) {
            const float4* src = (const float4*)xs + ((long)b * T_ + t0) * (D_ / 4) + tid;
            float4 acc = make_float4(0.f, 0.f, 0.f, 0.f);

            if (t0 + CH <= len) {
                // full slice: 32 rows, 8 independent loads in flight per iter
                #pragma unroll 1
                for (int r = 0; r < CH; r += 8) {
                    float4 v0 = src[0 * (D_ / 4)];
                    float4 v1 = src[1 * (D_ / 4)];
                    float4 v2 = src[2 * (D_ / 4)];
                    float4 v3 = src[3 * (D_ / 4)];
                    float4 v4 = src[4 * (D_ / 4)];
                    float4 v5 = src[5 * (D_ / 4)];
                    float4 v6 = src[6 * (D_ / 4)];
                    float4 v7 = src[7 * (D_ / 4)];
                    src += 8 * (D_ / 4);
                    acc.x += v0.x + v1.x + v2.x + v3.x + v4.x + v5.x + v6.x + v7.x;
                    acc.y += v0.y + v1.y + v2.y + v3.y + v4.y + v5.y + v6.y + v7.y;
                    acc.z += v0.z + v1.z + v2.z + v3.z + v4.z + v5.z + v6.z + v7.z;
                    acc.w += v0.w + v1.w + v2.w + v3.w + v4.w + v5.w + v6.w + v7.w;
                }
            } else {
                const int n = len - t0;   // partial tail slice
                for (int t = 0; t < n; ++t) {
                    float4 v = *src;
                    src += (D_ / 4);
                    acc.x += v.x; acc.y += v.y; acc.z += v.z; acc.w += v.w;
                }
            }
            ws[SLOT0_F4 + (long)s * (D_ / 4) + tid] = acc;
        }

        if (i + 1 < TAKES) {
            __syncthreads();            // sh_ticket updated
            t_next = sh_ticket;
        }
    }
}

__global__ __launch_bounds__(256) void mp_reduce(
    const float4* __restrict__ ws,
    const void* __restrict__ len_ptr,
    float* __restrict__ out)
{
    const int b = blockIdx.x >> 2;   // 4 blocks per sample
    const int c = blockIdx.x & 3;    // D-chunk: 256 floats = 64 float4
    const int lane = threadIdx.x & 63;
    const int w = threadIdx.x >> 6;  // 4 waves stride the slots

    const bool is64 = sniff64(len_ptr);
    const int len = load_len(len_ptr, is64, b);
    const int nact = (len + CH - 1) >> 5;   // ceil(len/32) in [1, 64]

    const int d4 = c * 64 + lane;    // float4 index in [0, 256)

    float4 acc = make_float4(0.f, 0.f, 0.f, 0.f);
    #pragma unroll 4
    for (int s = w; s < nact; s += 4) {
        float4 v = ws[SLOT0_F4 + (long)(b * 64 + s) * (D_ / 4) + d4];
        acc.x += v.x; acc.y += v.y; acc.z += v.z; acc.w += v.w;
    }

    __shared__ float4 sm[4][64];
    sm[w][lane] = acc;
    __syncthreads();

    if (w == 0) {
        float4 a0 = sm[0][lane], a1 = sm[1][lane], a2 = sm[2][lane], a3 = sm[3][lane];
        const float inv = 1.0f / (float)len;
        float4 r;
        r.x = (a0.x + a1.x + a2.x + a3.x) * inv;
        r.y = (a0.y + a1.y + a2.y + a3.y) * inv;
        r.z = (a0.z + a1.z + a2.z + a3.z) * inv;
        r.w = (a0.w + a1.w + a2.w + a3.w) * inv;
        ((float4*)out)[(long)b * (D_ / 4) + d4] = r;
    }
}

extern "C" void kernel_launch(void* const* d_in, const int* in_sizes, int n_in,
                              void* d_out, int out_size, void* d_ws, size_t ws_size,
                              hipStream_t stream)
{
    const float* xs = (const float*)d_in[0];
    const void* xs_len = d_in[1];
    float* out = (float*)d_out;
    unsigned* ctr = (unsigned*)d_ws;          // persistent rotating ticket counter
    float4* ws = (float4*)d_ws;               // slots at float4 index SLOT0_F4

    mp_partial<<<dim3(G1), dim3(256), 0, stream>>>(xs, xs_len, ctr, ws);
    mp_reduce<<<dim3(B_ * 4), dim3(256), 0, stream>>>(ws, xs_len, out);
}

// Round 8
// 29.546 us; speedup vs baseline: 4.8625x; 1.1105x over previous
//
#include <hip/hip_runtime.h>

// MeanPooling: xs [B=16, T=2048, D=1024] fp32, xs_len [B] (int64 or int32), out [B, D] fp32.
// out[b][d] = sum_{t < len_b} xs[b][t][d] / len_b
//
// Round 8: R2's exact streaming body + proportional partition at NB=512.
// Evidence: R2 (528 imbalanced 128KB streams) = 22.4 us beat R4 (1040 balanced
// 64KB streams) = 33.6 us and R7 (256 serialized blocks) = 32.8 us. Model:
// ~us-scale fixed cost per block-stream => fewer, longer, BALANCED streams.
//   K1: 528 blocks; block i -> (sample b, slot j) via array-free scan;
//       streams rows [j*len/cb, (j+1)*len/cb) (~32 rows, ~128 KB) into slot i.
//   K2: 64 blocks; reduce slots [s0, s0+cb) per sample, scale by 1/len, write.

#define B_ 16
#define T_ 2048
#define D_ 1024
#define NB 512           // target streams; sum(cnt) <= NB + B_ = 528
#define GRID1 (NB + B_)

__device__ __forceinline__ bool sniff64(const void* p)
{
    // int64 storage: element 0 read as i64 is in [1, T_]. int32 storage:
    // the i64 read = len0 | (len1 << 32) >= 2^32 since len1 >= 1.
    const long long v0 = ((const long long*)p)[0];
    return (v0 >= 1 && v0 <= (long long)T_);
}

__device__ __forceinline__ int load_len(const void* p, bool is64, int k)
{
    long long len = is64 ? ((const long long*)p)[k]
                         : (long long)((const int*)p)[k];
    if (len < 1) len = 1;
    if (len > T_) len = T_;
    return (int)len;
}

__global__ __launch_bounds__(256) void mp_partial(
    const float* __restrict__ xs,
    const void* __restrict__ len_ptr,
    float* __restrict__ ws)
{
    const int bid = blockIdx.x;
    const bool is64 = sniff64(len_ptr);

    unsigned total = 0;
    #pragma unroll
    for (int k = 0; k < B_; ++k) total += (unsigned)load_len(len_ptr, is64, k);

    // array-free prefix scan + select (rule #20: no runtime-indexed arrays)
    int b = -1, j = 0, len = 1, cb = 1;
    {
        unsigned p = 0;
        #pragma unroll
        for (int k = 0; k < B_; ++k) {
            const int lk = load_len(len_ptr, is64, k);
            const int ck = (int)(((unsigned)lk * NB + total - 1u) / total);  // >= 1
            const bool hit = (b < 0) && ((unsigned)bid < p + (unsigned)ck);
            if (hit) { b = k; j = bid - (int)p; len = lk; cb = ck; }
            p += (unsigned)ck;
        }
    }

    const int tid = threadIdx.x;     // 256 threads x float4 = full 1024-wide D row

    float4 acc = make_float4(0.f, 0.f, 0.f, 0.f);
    int r0 = 0, r1 = 0;
    if (b >= 0) {
        // products <= 2048*512 < 2^20 -> cheap u32 division
        r0 = (int)(((unsigned)j * (unsigned)len) / (unsigned)cb);
        r1 = (int)(((unsigned)(j + 1) * (unsigned)len) / (unsigned)cb);

        const float4* src = ((const float4*)xs) + ((long)b * T_ + r0) * (D_ / 4) + tid;
        #pragma unroll 4
        for (int t = r0; t < r1; ++t) {
            float4 v = *src;
            src += (D_ / 4);
            acc.x += v.x; acc.y += v.y; acc.z += v.z; acc.w += v.w;
        }
        // write unconditionally (zeros if r0==r1) so K2 reads are defined
        ((float4*)ws)[(long)bid * (D_ / 4) + tid] = acc;
    }
}

__global__ __launch_bounds__(256) void mp_reduce(
    const float* __restrict__ ws,
    const void* __restrict__ len_ptr,
    float* __restrict__ out)
{
    const int b = blockIdx.x >> 2;   // 4 blocks per sample
    const int c = blockIdx.x & 3;    // D-chunk: 256 floats = 64 float4
    const int lane = threadIdx.x & 63;
    const int w = threadIdx.x >> 6;  // 4 waves stride the slots

    const bool is64 = sniff64(len_ptr);

    unsigned total = 0;
    #pragma unroll
    for (int k = 0; k < B_; ++k) total += (unsigned)load_len(len_ptr, is64, k);

    int s0 = 0, cb = 1, len = 1;
    {
        unsigned p = 0;
        #pragma unroll
        for (int k = 0; k < B_; ++k) {
            const int lk = load_len(len_ptr, is64, k);
            const int ck = (int)(((unsigned)lk * NB + total - 1u) / total);
            if (k == b) { s0 = (int)p; cb = ck; len = lk; }
            p += (unsigned)ck;
        }
    }

    const int d4 = c * 64 + lane;    // float4 index in [0, 256)
    const float4* wsp = (const float4*)ws;

    float4 acc = make_float4(0.f, 0.f, 0.f, 0.f);
    for (int s = s0 + w; s < s0 + cb; s += 4) {
        float4 v = wsp[(long)s * (D_ / 4) + d4];
        acc.x += v.x; acc.y += v.y; acc.z += v.z; acc.w += v.w;
    }

    __shared__ float4 sm[4][64];
    sm[w][lane] = acc;
    __syncthreads();

    if (w == 0) {
        float4 a0 = sm[0][lane], a1 = sm[1][lane], a2 = sm[2][lane], a3 = sm[3][lane];
        const float inv = 1.0f / (float)len;
        float4 r;
        r.x = (a0.x + a1.x + a2.x + a3.x) * inv;
        r.y = (a0.y + a1.y + a2.y + a3.y) * inv;
        r.z = (a0.z + a1.z + a2.z + a3.z) * inv;
        r.w = (a0.w + a1.w + a2.w + a3.w) * inv;
        ((float4*)out)[(long)b * (D_ / 4) + d4] = r;
    }
}

extern "C" void kernel_launch(void* const* d_in, const int* in_sizes, int n_in,
                              void* d_out, int out_size, void* d_ws, size_t ws_size,
                              hipStream_t stream)
{
    const float* xs = (const float*)d_in[0];
    const void* xs_len = d_in[1];
    float* out = (float*)d_out;
    float* ws = (float*)d_ws;    // uses GRID1 * D_ * 4 B ~= 2.1 MiB

    mp_partial<<<dim3(GRID1), dim3(256), 0, stream>>>(xs, xs_len, ws);
    mp_reduce<<<dim3(B_ * 4), dim3(256), 0, stream>>>(ws, xs_len, out);
}